// Round 7
// baseline (818.963 us; speedup 1.0000x reference)
//
#include <hip/hip_runtime.h>

#define NP 784
#define DIM 384
#define NL 200000
#define WTOP_BLOCKS 512
#define WCAP2 1024

#define BM 128
#define BN 128
#define BK 32
#define NSTEP 12
#define MTILES 7
#define NTILES 1563
#define MPAD (MTILES * BM)     // 896
#define NLPAD (NTILES * BN)    // 200064
#define PCOLS (NTILES * 2)     // 3126 granules of 64 j's per i
#define DELTA2 2.0f            // margin on approx val (main min), err <= ~0.3 worst-case
#define DELTAW 6.0f            // margin for w_dist top-3 selection
#define RESCORE_WAVES 2048

typedef __attribute__((ext_vector_type(8))) short short8;
typedef __attribute__((ext_vector_type(4))) float f32x4;

__device__ __forceinline__ unsigned long long packdj(float d2, int j) {
  return ((unsigned long long)__float_as_uint(d2) << 32) | (unsigned int)j;
}

__device__ __forceinline__ void ins3(unsigned long long &t0, unsigned long long &t1,
                                     unsigned long long &t2, unsigned long long p) {
  if (p < t0) { t2 = t1; t1 = t0; t0 = p; }
  else if (p < t1) { t2 = t1; t1 = p; }
  else if (p < t2) { t2 = p; }
}

__device__ __forceinline__ unsigned short bf16rn(float x) {
  unsigned u = __float_as_uint(x);
  unsigned r = (u + 0x7fffu + ((u >> 16) & 1u)) >> 16;
  return (unsigned short)r;
}

__device__ __forceinline__ float bf16lo(unsigned u) { return __uint_as_float(u << 16); }
__device__ __forceinline__ float bf16hi(unsigned u) { return __uint_as_float(u & 0xFFFF0000u); }

// ================= prep A: patch -> Ah bf16 + a2 (exact fp32)  [verified R5] =========
__global__ __launch_bounds__(256) void k_prep_a(const float* __restrict__ patch,
                                                unsigned short* __restrict__ Ah,
                                                float* __restrict__ a2) {
  int i = (blockIdx.x << 2) | (threadIdx.x >> 6);
  int lane = threadIdx.x & 63;
  if (i >= MPAD) return;
  unsigned* orow = (unsigned*)(Ah + (size_t)i * DIM);
  if (i < NP) {
    const float* prow = patch + (size_t)i * DIM;
    float s = 0.f;
#pragma unroll
    for (int it = 0; it < 3; ++it) {
      float2 v = *(const float2*)(prow + (it << 7) + (lane << 1));
      s = fmaf(v.x, v.x, s); s = fmaf(v.y, v.y, s);
      orow[(it << 6) + lane] = (unsigned)bf16rn(v.x) | ((unsigned)bf16rn(v.y) << 16);
    }
#pragma unroll
    for (int m = 1; m < 64; m <<= 1) s += __shfl_xor(s, m);
    if (lane == 0) a2[i] = s;
  } else {
#pragma unroll
    for (int it = 0; it < 3; ++it) orow[(it << 6) + lane] = 0;
  }
}

// ================= prep B: lib -> Bh bf16 + b2 (pad rows: zero, b2=+inf)  [verified R5] =====
__global__ __launch_bounds__(256) void k_prep_b(const float* __restrict__ lib,
                                                unsigned short* __restrict__ Bh,
                                                float* __restrict__ b2) {
  int j = (blockIdx.x << 2) | (threadIdx.x >> 6);
  int lane = threadIdx.x & 63;
  if (j >= NLPAD) return;
  unsigned* orow = (unsigned*)(Bh + (size_t)j * DIM);
  if (j < NL) {
    const float* lrow = lib + (size_t)j * DIM;
    float s = 0.f;
#pragma unroll
    for (int it = 0; it < 3; ++it) {
      float2 v = *(const float2*)(lrow + (it << 7) + (lane << 1));
      s = fmaf(v.x, v.x, s); s = fmaf(v.y, v.y, s);
      orow[(it << 6) + lane] = (unsigned)bf16rn(v.x) | ((unsigned)bf16rn(v.y) << 16);
    }
#pragma unroll
    for (int m = 1; m < 64; m <<= 1) s += __shfl_xor(s, m);
    if (lane == 0) b2[j] = s;
  } else {
#pragma unroll
    for (int it = 0; it < 3; ++it) orow[(it << 6) + lane] = 0;
    if (lane == 0) b2[j] = INFINITY;
  }
}

// ====== main: 128x128 MFMA GEMM, BK=32, DOUBLE-BUFFERED 2-phase prefetch ======
// Per step: issue next-tile global_load_lds FIRST, then ds_read+MFMA current,
// then one __syncthreads (drains the overlapped prefetch). Swizzle scheme verified R2/R3.
__global__ __launch_bounds__(256, 4) void k_gemm(const unsigned short* __restrict__ Ah,
                                                 const unsigned short* __restrict__ Bh,
                                                 const float* __restrict__ b2,
                                                 float* __restrict__ partial) {
  __shared__ short sA[2 * 4096], sB[2 * 4096];   // 2 x 8KB each, 32KB total

  const int TOT = MTILES * NTILES;        // 10941
  const int q8 = TOT >> 3, r8 = TOT & 7;  // 1367, 5
  int xcd = blockIdx.x & 7, seq = blockIdx.x >> 3;
  int wg = (xcd < r8 ? xcd * (q8 + 1) : r8 * (q8 + 1) + (xcd - r8) * q8) + seq;
  int ntile = wg / MTILES;
  int mtile = wg - ntile * MTILES;
  const int i0 = mtile * BM;
  const int j0 = ntile * BN;

  const int t = threadIdx.x;
  const int w = t >> 6, lane = t & 63;
  const int wr = w >> 1, wc = w & 1;        // wave -> 64x64 sub-tile
  const int lrow = lane & 15, lk = lane >> 4;

  // staging sources (pre-swizzled k-chunk; verified R2/R3): 2 loads per matrix per step
  const unsigned short* srcs[4];
  short* dsts[4];
  {
    int dbase = w << 10;
#pragma unroll
    for (int p = 0; p < 2; ++p) {
      int c = (w << 7) + (p << 6) + lane;
      int row = c >> 2, kb = c & 3;
      int ks = ((kb ^ ((row >> 1) & 3)) << 3);
      srcs[0 + p] = Ah + (size_t)(i0 + row) * DIM + ks;
      srcs[2 + p] = Bh + (size_t)(j0 + row) * DIM + ks;
      dsts[0 + p] = sA + dbase + (p << 9);
      dsts[2 + p] = sB + dbase + (p << 9);
    }
  }

  // fragment LDS offsets (swizzled; verified R2/R3)
  int aoffs[4], boffs[4];
#pragma unroll
  for (int m = 0; m < 4; ++m) {
    int R = (wr << 6) + (m << 4) + lrow;
    aoffs[m] = (R << 5) + ((lk ^ ((R >> 1) & 3)) << 3);
  }
#pragma unroll
  for (int n = 0; n < 4; ++n) {
    int R = (wc << 6) + (n << 4) + lrow;
    boffs[n] = (R << 5) + ((lk ^ ((R >> 1) & 3)) << 3);
  }

  f32x4 acc[4][4];
#pragma unroll
  for (int m = 0; m < 4; ++m)
#pragma unroll
    for (int n = 0; n < 4; ++n) acc[m][n] = (f32x4){0.f, 0.f, 0.f, 0.f};

  // prologue: stage step 0 into buf 0, drain
#pragma unroll
  for (int e = 0; e < 4; ++e)
    __builtin_amdgcn_global_load_lds(
        (const __attribute__((address_space(1))) void*)(srcs[e]),
        (__attribute__((address_space(3))) void*)(dsts[e]), 16, 0, 0);
  __syncthreads();

#pragma unroll
  for (int step = 0; step < NSTEP; ++step) {
    const int cur = step & 1;
    const int curoff = cur << 12;          // cur*4096 shorts
    if (step < NSTEP - 1) {
      const int nxtoff = (cur ^ 1) << 12;
      const int k0 = (step + 1) << 5;      // shorts
#pragma unroll
      for (int e = 0; e < 4; ++e)
        __builtin_amdgcn_global_load_lds(
            (const __attribute__((address_space(1))) void*)(srcs[e] + k0),
            (__attribute__((address_space(3))) void*)(dsts[e] + nxtoff), 16, 0, 0);
    }
    short8 fa[4], fb[4];
#pragma unroll
    for (int m = 0; m < 4; ++m) fa[m] = *(const short8*)(sA + curoff + aoffs[m]);
#pragma unroll
    for (int n = 0; n < 4; ++n) fb[n] = *(const short8*)(sB + curoff + boffs[n]);
#pragma unroll
    for (int m = 0; m < 4; ++m)
#pragma unroll
      for (int n = 0; n < 4; ++n)
        acc[m][n] = __builtin_amdgcn_mfma_f32_16x16x32_bf16(fa[m], fb[n], acc[m][n], 0, 0, 0);
    if (step < NSTEP - 1) __syncthreads();   // drains prefetch (vmcnt0) + sync
  }

  // epilogue: val = min_n(b2[j] - 2*dot)  (a2[i] shift is constant per row -> added in scan)
  float b2v[4];
#pragma unroll
  for (int n = 0; n < 4; ++n) b2v[n] = b2[j0 + (wc << 6) + (n << 4) + lrow];
#pragma unroll
  for (int m = 0; m < 4; ++m) {
    int ibase = i0 + (wr << 6) + (m << 4) + (lk << 2);
#pragma unroll
    for (int r = 0; r < 4; ++r) {
      int i = ibase + r;
      float dm = INFINITY;
#pragma unroll
      for (int n = 0; n < 4; ++n)
        dm = fminf(dm, fmaf(-2.f, acc[m][n][r], b2v[n]));
#pragma unroll
      for (int mm = 1; mm < 16; mm <<= 1)
        dm = fminf(dm, __shfl_xor(dm, mm));
      if (lrow == 0 && i < NP)
        partial[(size_t)i * PCOLS + (ntile << 1) + wc] = dm;
    }
  }
}

// ===== scan granule mins per i; select candidates within margin -> compacted list =====
__global__ __launch_bounds__(256) void k_scan_select(const float* __restrict__ partial,
                                                     unsigned int* __restrict__ list,
                                                     unsigned int* __restrict__ cnt) {
  __shared__ float red[256];
  __shared__ float thr;
  int i = blockIdx.x;
  int t = threadIdx.x;
  const float* row = partial + (size_t)i * PCOLS;
  float best = INFINITY;
  for (int e = t; e < PCOLS; e += 256) best = fminf(best, row[e]);
  red[t] = best;
  __syncthreads();
  for (int s = 128; s > 0; s >>= 1) {
    if (t < s) red[t] = fminf(red[t], red[t + s]);
    __syncthreads();
  }
  if (t == 0) thr = red[0] + DELTA2;
  __syncthreads();
  float th = thr;
  for (int e = t; e < PCOLS; e += 256) {
    if (row[e] <= th) {
      unsigned int pos = atomicAdd(cnt, 1u);
      list[pos] = ((unsigned int)i << 12) | (unsigned int)e;
    }
  }
}

// ===== exact fp32 rescore of candidate granules -> pmin (packed atomicMin) =====
__global__ __launch_bounds__(256) void k_rescore(const unsigned int* __restrict__ list,
                                                 const unsigned int* __restrict__ cnt,
                                                 const float* __restrict__ patch,
                                                 const float* __restrict__ lib,
                                                 const float* __restrict__ a2,
                                                 const float* __restrict__ b2,
                                                 unsigned long long* __restrict__ pmin) {
  int wid = (blockIdx.x << 2) | (threadIdx.x >> 6);
  int lane = threadIdx.x & 63;
  int n = (int)*cnt;
  for (int c = wid; c < n; c += RESCORE_WAVES) {
    unsigned int e = list[c];
    int i = (int)(e >> 12);
    int g = (int)(e & 4095u);
    int j = (g << 6) + lane;
    unsigned long long best = ~0ull;
    if (j < NL) {
      const float* pr = patch + (size_t)i * DIM;
      const float* lr = lib + (size_t)j * DIM;
      float d0 = 0.f, d1 = 0.f, d2s = 0.f, d3 = 0.f;
#pragma unroll 8
      for (int k = 0; k < DIM; k += 4) {
        float4 lv = *(const float4*)(lr + k);
        float4 pv = *(const float4*)(pr + k);
        d0 = fmaf(lv.x, pv.x, d0);
        d1 = fmaf(lv.y, pv.y, d1);
        d2s = fmaf(lv.z, pv.z, d2s);
        d3 = fmaf(lv.w, pv.w, d3);
      }
      float dot = (d0 + d1) + (d2s + d3);
      float d2 = fmaxf(a2[i] + b2[j] - 2.f * dot, 0.f);
      best = packdj(d2, j);
    }
#pragma unroll
    for (int mm = 1; mm < 64; mm <<= 1) {
      unsigned long long o = __shfl_xor(best, mm);
      best = (o < best) ? o : best;
    }
    if (lane == 0) atomicMin(pmin + i, best);
  }
}

// ---------- finalize1: min_val = sqrt(d2min); s_star/s_idx (jnp tie-break) ----------
__global__ __launch_bounds__(256) void k_final1(const unsigned long long* __restrict__ pmin,
                                                float* __restrict__ minval,
                                                float* __restrict__ scalf,
                                                int* __restrict__ scali) {
  __shared__ float sv[256];
  __shared__ int si[256];
  int t = threadIdx.x;
  float bv = -1.f; int bi = 1 << 30;
  for (int i = t; i < NP; i += 256) {
    unsigned long long p = pmin[i];
    float d2 = __uint_as_float((unsigned int)(p >> 32));
    float v = sqrtf(d2);
    minval[i] = v;
    if (v > bv) { bv = v; bi = i; }
  }
  sv[t] = bv; si[t] = bi;
  __syncthreads();
  for (int s = 128; s > 0; s >>= 1) {
    if (t < s) {
      if (sv[t + s] > sv[t] || (sv[t + s] == sv[t] && si[t + s] < si[t])) {
        sv[t] = sv[t + s]; si[t] = si[t + s];
      }
    }
    __syncthreads();
  }
  if (t == 0) {
    scalf[0] = sv[0];
    scali[0] = si[0];
    scali[1] = (int)(unsigned int)(pmin[si[0]] & 0xFFFFFFFFull);
  }
}

// ---------- bilinear 28x28 -> 224x224 ----------
__global__ __launch_bounds__(256) void k_resize(const float* __restrict__ mv,
                                                float* __restrict__ out) {
  int o = blockIdx.x * 256 + threadIdx.x;
  if (o >= 224 * 224) return;
  int y = o / 224, x = o - y * 224;
  float sy = (y + 0.5f) * 0.125f - 0.5f;
  float sx = (x + 0.5f) * 0.125f - 0.5f;
  int y0 = (int)floorf(sy); float fy = sy - (float)y0;
  int x0 = (int)floorf(sx); float fx = sx - (float)x0;
  int y0c = max(y0, 0), y1c = min(y0 + 1, 27);
  int x0c = max(x0, 0), x1c = min(x0 + 1, 27);
  float v00 = mv[y0c * 28 + x0c], v01 = mv[y0c * 28 + x1c];
  float v10 = mv[y1c * 28 + x0c], v11 = mv[y1c * 28 + x1c];
  float v0 = v00 + fx * (v01 - v00);
  float v1 = v10 + fx * (v11 - v10);
  out[1 + o] = v0 + fy * (v1 - v0);
}

// ===== approx w_dist^2 via Bh (bf16) GEMV; store wd2[j]; per-block top-3  [verified R5] =====
__global__ __launch_bounds__(256) void k_wdist(const unsigned short* __restrict__ Bh,
                                               const float* __restrict__ b2,
                                               const int* __restrict__ scali,
                                               float* __restrict__ wd2,
                                               unsigned long long* __restrict__ top3w) {
  __shared__ unsigned long long sm[12];
  int wave = threadIdx.x >> 6, lane = threadIdx.x & 63;
  int jstar = scali[1];
  const unsigned* msrow = (const unsigned*)(Bh + (size_t)jstar * DIM);
  float ms[6];
#pragma unroll
  for (int it = 0; it < 3; ++it) {
    unsigned u = msrow[(it << 6) + lane];
    ms[it * 2] = bf16lo(u);
    ms[it * 2 + 1] = bf16hi(u);
  }
  float bstar = b2[jstar];
  unsigned long long t0 = ~0ull, t1 = ~0ull, t2 = ~0ull;
  int gw = (blockIdx.x << 2) | wave;
  for (int j = gw; j < NL; j += WTOP_BLOCKS * 4) {
    const unsigned* row = (const unsigned*)(Bh + (size_t)j * DIM);
    float dot = 0.f;
#pragma unroll
    for (int it = 0; it < 3; ++it) {
      unsigned u = row[(it << 6) + lane];
      dot = fmaf(ms[it * 2], bf16lo(u), dot);
      dot = fmaf(ms[it * 2 + 1], bf16hi(u), dot);
    }
#pragma unroll
    for (int mm = 1; mm < 64; mm <<= 1) dot += __shfl_xor(dot, mm);
    float d2 = fmaxf(bstar + b2[j] - 2.f * dot, 0.f);
    if (lane == 0) wd2[j] = d2;
    ins3(t0, t1, t2, packdj(d2, j));
  }
  if (lane == 0) { sm[wave * 3] = t0; sm[wave * 3 + 1] = t1; sm[wave * 3 + 2] = t2; }
  __syncthreads();
  if (threadIdx.x == 0) {
    unsigned long long a0 = ~0ull, a1 = ~0ull, a2v = ~0ull;
    for (int e = 0; e < 12; ++e) ins3(a0, a1, a2v, sm[e]);
    top3w[blockIdx.x * 3 + 0] = a0;
    top3w[blockIdx.x * 3 + 1] = a1;
    top3w[blockIdx.x * 3 + 2] = a2v;
  }
}

// ===== merged w-tail: top3 merge -> threshold -> collect -> exact rescore -> final s =====
__global__ __launch_bounds__(256) void k_wfinal(const float* __restrict__ patch,
                                                const float* __restrict__ lib,
                                                const float* __restrict__ b2,
                                                const float* __restrict__ wd2,
                                                const unsigned long long* __restrict__ top3w,
                                                const float* __restrict__ scalf,
                                                const int* __restrict__ scali,
                                                float* __restrict__ out) {
  __shared__ unsigned long long sm[768];
  __shared__ unsigned long long pk[WCAP2];
  __shared__ int wl[WCAP2];
  __shared__ unsigned int wn;
  __shared__ float thrS;
  __shared__ int snn[2];
  __shared__ float sd[2];
  int t = threadIdx.x, wv = t >> 6, lane = t & 63;

  unsigned long long t0 = ~0ull, t1 = ~0ull, t2 = ~0ull;
  for (int e = t; e < WTOP_BLOCKS * 3; e += 256) ins3(t0, t1, t2, top3w[e]);
  sm[t] = t0; sm[256 + t] = t1; sm[512 + t] = t2;
  if (t == 0) wn = 0;
  __syncthreads();
  if (t == 0) {
    unsigned long long a0 = ~0ull, a1 = ~0ull, a2v = ~0ull;
    for (int e = 0; e < 768; ++e) ins3(a0, a1, a2v, sm[e]);
    thrS = __uint_as_float((unsigned int)(a2v >> 32)) + DELTAW;
  }
  __syncthreads();
  float thr = thrS;
  for (int j = t; j < NL; j += 256) {
    if (wd2[j] <= thr) {
      unsigned int pos = atomicAdd(&wn, 1u);
      if (pos < WCAP2) wl[pos] = j;
    }
  }
  __syncthreads();
  int n = min((int)wn, WCAP2);
  int jstar = scali[1];
  const float* mstar = lib + (size_t)jstar * DIM;
  float bstar = b2[jstar];
  for (int c = wv; c < n; c += 4) {
    int j = wl[c];
    const float* lr = lib + (size_t)j * DIM;
    float s = 0.f;
#pragma unroll
    for (int q = 0; q < 6; ++q)
      s = fmaf(mstar[lane + (q << 6)], lr[lane + (q << 6)], s);
#pragma unroll
    for (int mm = 1; mm < 64; mm <<= 1) s += __shfl_xor(s, mm);
    if (lane == 0) pk[c] = packdj(fmaxf(bstar + b2[j] - 2.f * s, 0.f), j);
  }
  __syncthreads();
  if (t == 0) {
    unsigned long long a0 = ~0ull, a1 = ~0ull, a2v = ~0ull;
    for (int e = 0; e < n; ++e) ins3(a0, a1, a2v, pk[e]);
    snn[0] = (int)(unsigned int)(a1 & 0xFFFFFFFFull);   // nn_idx[1]
    snn[1] = (int)(unsigned int)(a2v & 0xFFFFFFFFull);  // nn_idx[2]
  }
  __syncthreads();
  if (t < 128) {
    const float* mt = patch + (size_t)scali[0] * DIM;
    const float* bp = lib + (size_t)snn[wv] * DIM;
    float s = 0.f;
#pragma unroll
    for (int q = 0; q < 6; ++q) {
      float d = mt[lane + (q << 6)] - bp[lane + (q << 6)];
      s = fmaf(d, d, s);
    }
#pragma unroll
    for (int mm = 1; mm < 64; mm <<= 1) s += __shfl_xor(s, mm);
    if (lane == 0) sd[wv] = sqrtf(fmaxf(s, 0.f));
  }
  __syncthreads();
  if (t == 0) {
    const float Ds = 19.595917942265423f;  // sqrt(384)
    float sstar = scalf[0];
    float w = 1.f - expf(sstar / Ds) / (expf(sd[0] / Ds) + expf(sd[1] / Ds));
    out[0] = w * sstar;
  }
}

// ======= fallback fp32 path kernels (used only if ws_size is too small) =======
__global__ __launch_bounds__(256) void k_norms(const float* __restrict__ patch,
                                               const float* __restrict__ lib,
                                               float* __restrict__ a2,
                                               float* __restrict__ b2) {
  int wave = (blockIdx.x << 2) | (threadIdx.x >> 6);
  int lane = threadIdx.x & 63;
  const int NR = NL + NP;
  if (wave >= NR) return;
  const float* src = (wave < NL) ? (lib + (size_t)wave * DIM)
                                 : (patch + (size_t)(wave - NL) * DIM);
  float s = 0.f;
#pragma unroll
  for (int m = 0; m < 6; ++m) { float v = src[lane + (m << 6)]; s += v * v; }
#pragma unroll
  for (int m = 1; m < 64; m <<= 1) s += __shfl_xor(s, m);
  if (lane == 0) { if (wave < NL) b2[wave] = s; else a2[wave - NL] = s; }
}

__global__ __launch_bounds__(256) void k_distmin(const float* __restrict__ patch,
                                                 const float* __restrict__ lib,
                                                 const float* __restrict__ a2,
                                                 const float* __restrict__ b2,
                                                 unsigned long long* __restrict__ pmin) {
  __shared__ float As[16][68];
  __shared__ float Bs[16][68];
  const int t = threadIdx.x;
  const int lr = t >> 2;
  const int lc = (t & 3) << 2;
  const int ti = t >> 4;
  const int tj = t & 15;
  const int i0 = blockIdx.y << 6;
  const int j0 = blockIdx.x << 6;
  const bool a_ok = (i0 + lr) < NP;
  const float* ap = patch + (size_t)(i0 + lr) * DIM + lc;
  const float* bp = lib + (size_t)(j0 + lr) * DIM + lc;

  float acc[4][4] = {};
  for (int k0 = 0; k0 < DIM; k0 += 16) {
    float4 avv = make_float4(0.f, 0.f, 0.f, 0.f);
    if (a_ok) avv = *(const float4*)(ap + k0);
    float4 bvv = *(const float4*)(bp + k0);
    __syncthreads();
    As[lc + 0][lr] = avv.x; As[lc + 1][lr] = avv.y;
    As[lc + 2][lr] = avv.z; As[lc + 3][lr] = avv.w;
    Bs[lc + 0][lr] = bvv.x; Bs[lc + 1][lr] = bvv.y;
    Bs[lc + 2][lr] = bvv.z; Bs[lc + 3][lr] = bvv.w;
    __syncthreads();
#pragma unroll
    for (int kk = 0; kk < 16; ++kk) {
      float4 a = *(const float4*)&As[kk][ti << 2];
      float4 b = *(const float4*)&Bs[kk][tj << 2];
      acc[0][0] += a.x * b.x; acc[0][1] += a.x * b.y; acc[0][2] += a.x * b.z; acc[0][3] += a.x * b.w;
      acc[1][0] += a.y * b.x; acc[1][1] += a.y * b.y; acc[1][2] += a.y * b.z; acc[1][3] += a.y * b.w;
      acc[2][0] += a.z * b.x; acc[2][1] += a.z * b.y; acc[2][2] += a.z * b.z; acc[2][3] += a.z * b.w;
      acc[3][0] += a.w * b.x; acc[3][1] += a.w * b.y; acc[3][2] += a.w * b.z; acc[3][3] += a.w * b.w;
    }
  }
#pragma unroll
  for (int r = 0; r < 4; ++r) {
    int i = i0 + (ti << 2) + r;
    unsigned long long best = ~0ull;
    if (i < NP) {
      float ai = a2[i];
#pragma unroll
      for (int c = 0; c < 4; ++c) {
        int j = j0 + (tj << 2) + c;
        float d2 = fmaxf(ai + b2[j] - 2.f * acc[r][c], 0.f);
        unsigned long long p = packdj(d2, j);
        best = (p < best) ? p : best;
      }
    }
#pragma unroll
    for (int m = 1; m < 16; m <<= 1) {
      unsigned long long o = __shfl_xor(best, m);
      best = (o < best) ? o : best;
    }
    if (tj == 0 && i < NP) atomicMin(pmin + i, best);
  }
}

__global__ __launch_bounds__(256) void k_wtop(const float* __restrict__ lib,
                                              const int* __restrict__ scali,
                                              unsigned long long* __restrict__ top3) {
  __shared__ unsigned long long sm[12];
  int wave = threadIdx.x >> 6, lane = threadIdx.x & 63;
  int jstar = scali[1];
  const float* ms = lib + (size_t)jstar * DIM;
  float m[6];
#pragma unroll
  for (int q = 0; q < 6; ++q) m[q] = ms[lane + (q << 6)];
  unsigned long long t0 = ~0ull, t1 = ~0ull, t2 = ~0ull;
  int gw = (blockIdx.x << 2) | wave;
  for (int j = gw; j < NL; j += WTOP_BLOCKS * 4) {
    const float* bp = lib + (size_t)j * DIM;
    float s = 0.f;
#pragma unroll
    for (int q = 0; q < 6; ++q) { float d = bp[lane + (q << 6)] - m[q]; s += d * d; }
#pragma unroll
    for (int mm = 1; mm < 64; mm <<= 1) s += __shfl_xor(s, mm);
    ins3(t0, t1, t2, packdj(fmaxf(s, 0.f), j));
  }
  if (lane == 0) { sm[wave * 3] = t0; sm[wave * 3 + 1] = t1; sm[wave * 3 + 2] = t2; }
  __syncthreads();
  if (threadIdx.x == 0) {
    unsigned long long a0 = ~0ull, a1 = ~0ull, a2v = ~0ull;
    for (int e = 0; e < 12; ++e) ins3(a0, a1, a2v, sm[e]);
    top3[blockIdx.x * 3 + 0] = a0;
    top3[blockIdx.x * 3 + 1] = a1;
    top3[blockIdx.x * 3 + 2] = a2v;
  }
}

__global__ __launch_bounds__(256) void k_finals(const float* __restrict__ patch,
                                                const float* __restrict__ lib,
                                                const unsigned long long* __restrict__ top3,
                                                const float* __restrict__ scalf,
                                                const int* __restrict__ scali,
                                                float* __restrict__ out) {
  __shared__ unsigned long long sm[768];
  __shared__ int snn[2];
  __shared__ float sd[2];
  int t = threadIdx.x;
  unsigned long long t0 = ~0ull, t1 = ~0ull, t2 = ~0ull;
  for (int e = t; e < WTOP_BLOCKS * 3; e += 256) ins3(t0, t1, t2, top3[e]);
  sm[t] = t0; sm[256 + t] = t1; sm[512 + t] = t2;
  __syncthreads();
  if (t == 0) {
    unsigned long long a0 = ~0ull, a1 = ~0ull, a2v = ~0ull;
    for (int e = 0; e < 768; ++e) ins3(a0, a1, a2v, sm[e]);
    snn[0] = (int)(unsigned int)(a1 & 0xFFFFFFFFull);
    snn[1] = (int)(unsigned int)(a2v & 0xFFFFFFFFull);
  }
  __syncthreads();
  if (t < 128) {
    int wv = t >> 6, lane = t & 63;
    const float* mt = patch + (size_t)scali[0] * DIM;
    const float* bp = lib + (size_t)snn[wv] * DIM;
    float s = 0.f;
#pragma unroll
    for (int q = 0; q < 6; ++q) {
      float d = mt[lane + (q << 6)] - bp[lane + (q << 6)];
      s += d * d;
    }
#pragma unroll
    for (int mm = 1; mm < 64; mm <<= 1) s += __shfl_xor(s, mm);
    if (lane == 0) sd[wv] = sqrtf(fmaxf(s, 0.f));
  }
  __syncthreads();
  if (t == 0) {
    const float Ds = 19.595917942265423f;
    float sstar = scalf[0];
    float w = 1.f - expf(sstar / Ds) / (expf(sd[0] / Ds) + expf(sd[1] / Ds));
    out[0] = w * sstar;
  }
}

extern "C" void kernel_launch(void* const* d_in, const int* in_sizes, int n_in,
                              void* d_out, int out_size, void* d_ws, size_t ws_size,
                              hipStream_t stream) {
  const float* patch = (const float*)d_in[0];
  const float* lib = (const float*)d_in[1];
  float* out = (float*)d_out;
  char* ws = (char*)d_ws;

  const size_t SZ_BPLANE = (size_t)NLPAD * DIM * 2;          // 153,649,152
  const size_t SZ_APLANE = (size_t)MPAD * DIM * 2;           // 688,128
  const size_t SZ_PART = (size_t)NP * PCOLS * 4;             // 9,803,136
  const size_t SZ_LIST = (size_t)NP * PCOLS * 4;             // 9,803,136
  const size_t SZ_WD2 = (size_t)NLPAD * 4;                   // 800,256
  const size_t NEED = SZ_BPLANE + SZ_APLANE + SZ_PART + SZ_LIST + SZ_WD2 + 4 * 1024 * 1024;

  if (ws_size >= NEED) {
    size_t off = 0;
    unsigned short* Bh = (unsigned short*)(ws + off); off += SZ_BPLANE;
    unsigned short* Ah = (unsigned short*)(ws + off); off += SZ_APLANE;
    float* partial = (float*)(ws + off); off += SZ_PART;
    unsigned int* list = (unsigned int*)(ws + off); off += SZ_LIST;
    float* wd2 = (float*)(ws + off); off += SZ_WD2;
    float* b2 = (float*)(ws + off); off += (size_t)NLPAD * 4;
    float* a2 = (float*)(ws + off); off += (size_t)MPAD * 4;
    unsigned long long* pmin = (unsigned long long*)(ws + off); off += NP * 8;
    unsigned long long* top3w = (unsigned long long*)(ws + off); off += WTOP_BLOCKS * 3 * 8;
    float* minval = (float*)(ws + off); off += NP * 4;
    float* scalf = (float*)(ws + off); off += 16;
    int* scali = (int*)(ws + off); off += 16;
    unsigned int* cnt = (unsigned int*)(ws + off); off += 16;

    hipMemsetAsync(pmin, 0xFF, NP * sizeof(unsigned long long), stream);
    hipMemsetAsync(cnt, 0, 16, stream);

    k_prep_a<<<MPAD / 4, 256, 0, stream>>>(patch, Ah, a2);
    k_prep_b<<<NLPAD / 4, 256, 0, stream>>>(lib, Bh, b2);
    k_gemm<<<MTILES * NTILES, 256, 0, stream>>>(Ah, Bh, b2, partial);
    k_scan_select<<<NP, 256, 0, stream>>>(partial, list, cnt);
    k_rescore<<<RESCORE_WAVES / 4, 256, 0, stream>>>(list, cnt, patch, lib, a2, b2, pmin);
    k_final1<<<1, 256, 0, stream>>>(pmin, minval, scalf, scali);
    k_resize<<<(224 * 224 + 255) / 256, 256, 0, stream>>>(minval, out);
    k_wdist<<<WTOP_BLOCKS, 256, 0, stream>>>(Bh, b2, scali, wd2, top3w);
    k_wfinal<<<1, 256, 0, stream>>>(patch, lib, b2, wd2, top3w, scalf, scali, out);
  } else {
    // fallback: fp32 VALU path (verified R1)
    float* b2 = (float*)ws;
    float* a2 = (float*)(ws + 800000);
    unsigned long long* pmin = (unsigned long long*)(ws + 803200);
    unsigned long long* top3 = (unsigned long long*)(ws + 809472);
    float* minval = (float*)(ws + 821760);
    float* scalf = (float*)(ws + 824896);
    int* scali = (int*)(ws + 824912);

    hipMemsetAsync(pmin, 0xFF, NP * sizeof(unsigned long long), stream);
    k_norms<<<(NL + NP + 3) / 4, 256, 0, stream>>>(patch, lib, a2, b2);
    dim3 grid(NL / 64, (NP + 63) / 64);
    k_distmin<<<grid, 256, 0, stream>>>(patch, lib, a2, b2, pmin);
    k_final1<<<1, 256, 0, stream>>>(pmin, minval, scalf, scali);
    k_resize<<<(224 * 224 + 255) / 256, 256, 0, stream>>>(minval, out);
    k_wtop<<<WTOP_BLOCKS, 256, 0, stream>>>(lib, scali, top3);
    k_finals<<<1, 256, 0, stream>>>(patch, lib, top3, scalf, scali, out);
  }
}

// Round 8
// 606.541 us; speedup vs baseline: 1.3502x; 1.3502x over previous
//
#include <hip/hip_runtime.h>

#define NP 784
#define DIM 384
#define NL 200000
#define WTOP_BLOCKS 512
#define WCAP 4096

#define BM 128
#define BN 128
#define BK 32
#define NSTEP 12
#define MTILES 7
#define NTILES 1563
#define MPAD (MTILES * BM)     // 896
#define NLPAD (NTILES * BN)    // 200064
#define PCOLS (NTILES * 2)     // 3126 granules of 64 j's per i
#define DELTA2 2.0f            // margin on approx val (main min)
#define DELTAW 6.0f            // margin for w_dist top-3 selection
#define RESCORE_WAVES 2048

typedef __attribute__((ext_vector_type(8))) short short8;
typedef __attribute__((ext_vector_type(4))) float f32x4;

__device__ __forceinline__ unsigned long long packdj(float d2, int j) {
  return ((unsigned long long)__float_as_uint(d2) << 32) | (unsigned int)j;
}

__device__ __forceinline__ void ins3(unsigned long long &t0, unsigned long long &t1,
                                     unsigned long long &t2, unsigned long long p) {
  if (p < t0) { t2 = t1; t1 = t0; t0 = p; }
  else if (p < t1) { t2 = t1; t1 = p; }
  else if (p < t2) { t2 = p; }
}

__device__ __forceinline__ unsigned short bf16rn(float x) {
  unsigned u = __float_as_uint(x);
  unsigned r = (u + 0x7fffu + ((u >> 16) & 1u)) >> 16;
  return (unsigned short)r;
}

__device__ __forceinline__ float bf16lo(unsigned u) { return __uint_as_float(u << 16); }
__device__ __forceinline__ float bf16hi(unsigned u) { return __uint_as_float(u & 0xFFFF0000u); }

// ================= prep A: patch -> Ah bf16 + a2 (exact fp32)  [verified R5] =========
__global__ __launch_bounds__(256) void k_prep_a(const float* __restrict__ patch,
                                                unsigned short* __restrict__ Ah,
                                                float* __restrict__ a2) {
  int i = (blockIdx.x << 2) | (threadIdx.x >> 6);
  int lane = threadIdx.x & 63;
  if (i >= MPAD) return;
  unsigned* orow = (unsigned*)(Ah + (size_t)i * DIM);
  if (i < NP) {
    const float* prow = patch + (size_t)i * DIM;
    float s = 0.f;
#pragma unroll
    for (int it = 0; it < 3; ++it) {
      float2 v = *(const float2*)(prow + (it << 7) + (lane << 1));
      s = fmaf(v.x, v.x, s); s = fmaf(v.y, v.y, s);
      orow[(it << 6) + lane] = (unsigned)bf16rn(v.x) | ((unsigned)bf16rn(v.y) << 16);
    }
#pragma unroll
    for (int m = 1; m < 64; m <<= 1) s += __shfl_xor(s, m);
    if (lane == 0) a2[i] = s;
  } else {
#pragma unroll
    for (int it = 0; it < 3; ++it) orow[(it << 6) + lane] = 0;
  }
}

// ================= prep B: lib -> Bh bf16 + b2 (pad rows: zero, b2=+inf)  [verified R5] =====
__global__ __launch_bounds__(256) void k_prep_b(const float* __restrict__ lib,
                                                unsigned short* __restrict__ Bh,
                                                float* __restrict__ b2) {
  int j = (blockIdx.x << 2) | (threadIdx.x >> 6);
  int lane = threadIdx.x & 63;
  if (j >= NLPAD) return;
  unsigned* orow = (unsigned*)(Bh + (size_t)j * DIM);
  if (j < NL) {
    const float* lrow = lib + (size_t)j * DIM;
    float s = 0.f;
#pragma unroll
    for (int it = 0; it < 3; ++it) {
      float2 v = *(const float2*)(lrow + (it << 7) + (lane << 1));
      s = fmaf(v.x, v.x, s); s = fmaf(v.y, v.y, s);
      orow[(it << 6) + lane] = (unsigned)bf16rn(v.x) | ((unsigned)bf16rn(v.y) << 16);
    }
#pragma unroll
    for (int m = 1; m < 64; m <<= 1) s += __shfl_xor(s, m);
    if (lane == 0) b2[j] = s;
  } else {
#pragma unroll
    for (int it = 0; it < 3; ++it) orow[(it << 6) + lane] = 0;
    if (lane == 0) b2[j] = INFINITY;
  }
}

// ====== main: 128x128 MFMA GEMM, BK=32, double-buffered 2-phase prefetch [R7] ======
__global__ __launch_bounds__(256, 4) void k_gemm(const unsigned short* __restrict__ Ah,
                                                 const unsigned short* __restrict__ Bh,
                                                 const float* __restrict__ b2,
                                                 float* __restrict__ partial) {
  __shared__ short sA[2 * 4096], sB[2 * 4096];   // 32KB total

  const int TOT = MTILES * NTILES;        // 10941
  const int q8 = TOT >> 3, r8 = TOT & 7;  // 1367, 5
  int xcd = blockIdx.x & 7, seq = blockIdx.x >> 3;
  int wg = (xcd < r8 ? xcd * (q8 + 1) : r8 * (q8 + 1) + (xcd - r8) * q8) + seq;
  int ntile = wg / MTILES;
  int mtile = wg - ntile * MTILES;
  const int i0 = mtile * BM;
  const int j0 = ntile * BN;

  const int t = threadIdx.x;
  const int w = t >> 6, lane = t & 63;
  const int wr = w >> 1, wc = w & 1;        // wave -> 64x64 sub-tile
  const int lrow = lane & 15, lk = lane >> 4;

  const unsigned short* srcs[4];
  short* dsts[4];
  {
    int dbase = w << 10;
#pragma unroll
    for (int p = 0; p < 2; ++p) {
      int c = (w << 7) + (p << 6) + lane;
      int row = c >> 2, kb = c & 3;
      int ks = ((kb ^ ((row >> 1) & 3)) << 3);
      srcs[0 + p] = Ah + (size_t)(i0 + row) * DIM + ks;
      srcs[2 + p] = Bh + (size_t)(j0 + row) * DIM + ks;
      dsts[0 + p] = sA + dbase + (p << 9);
      dsts[2 + p] = sB + dbase + (p << 9);
    }
  }

  int aoffs[4], boffs[4];
#pragma unroll
  for (int m = 0; m < 4; ++m) {
    int R = (wr << 6) + (m << 4) + lrow;
    aoffs[m] = (R << 5) + ((lk ^ ((R >> 1) & 3)) << 3);
  }
#pragma unroll
  for (int n = 0; n < 4; ++n) {
    int R = (wc << 6) + (n << 4) + lrow;
    boffs[n] = (R << 5) + ((lk ^ ((R >> 1) & 3)) << 3);
  }

  f32x4 acc[4][4];
#pragma unroll
  for (int m = 0; m < 4; ++m)
#pragma unroll
    for (int n = 0; n < 4; ++n) acc[m][n] = (f32x4){0.f, 0.f, 0.f, 0.f};

  // prologue: stage step 0 into buf 0, drain
#pragma unroll
  for (int e = 0; e < 4; ++e)
    __builtin_amdgcn_global_load_lds(
        (const __attribute__((address_space(1))) void*)(srcs[e]),
        (__attribute__((address_space(3))) void*)(dsts[e]), 16, 0, 0);
  __syncthreads();

#pragma unroll
  for (int step = 0; step < NSTEP; ++step) {
    const int cur = step & 1;
    const int curoff = cur << 12;
    if (step < NSTEP - 1) {
      const int nxtoff = (cur ^ 1) << 12;
      const int k0 = (step + 1) << 5;
#pragma unroll
      for (int e = 0; e < 4; ++e)
        __builtin_amdgcn_global_load_lds(
            (const __attribute__((address_space(1))) void*)(srcs[e] + k0),
            (__attribute__((address_space(3))) void*)(dsts[e] + nxtoff), 16, 0, 0);
    }
    short8 fa[4], fb[4];
#pragma unroll
    for (int m = 0; m < 4; ++m) fa[m] = *(const short8*)(sA + curoff + aoffs[m]);
#pragma unroll
    for (int n = 0; n < 4; ++n) fb[n] = *(const short8*)(sB + curoff + boffs[n]);
#pragma unroll
    for (int m = 0; m < 4; ++m)
#pragma unroll
      for (int n = 0; n < 4; ++n)
        acc[m][n] = __builtin_amdgcn_mfma_f32_16x16x32_bf16(fa[m], fb[n], acc[m][n], 0, 0, 0);
    if (step < NSTEP - 1) __syncthreads();
  }

  // epilogue: val = min_n(b2[j] - 2*dot)  (a2 shift constant per row; handled in rescore)
  float b2v[4];
#pragma unroll
  for (int n = 0; n < 4; ++n) b2v[n] = b2[j0 + (wc << 6) + (n << 4) + lrow];
#pragma unroll
  for (int m = 0; m < 4; ++m) {
    int ibase = i0 + (wr << 6) + (m << 4) + (lk << 2);
#pragma unroll
    for (int r = 0; r < 4; ++r) {
      int i = ibase + r;
      float dm = INFINITY;
#pragma unroll
      for (int n = 0; n < 4; ++n)
        dm = fminf(dm, fmaf(-2.f, acc[m][n][r], b2v[n]));
#pragma unroll
      for (int mm = 1; mm < 16; mm <<= 1)
        dm = fminf(dm, __shfl_xor(dm, mm));
      if (lrow == 0 && i < NP)
        partial[(size_t)i * PCOLS + (ntile << 1) + wc] = dm;
    }
  }
}

// ===== scan granule mins per i; select candidates within margin -> compacted list =====
__global__ __launch_bounds__(256) void k_scan_select(const float* __restrict__ partial,
                                                     unsigned int* __restrict__ list,
                                                     unsigned int* __restrict__ cnt) {
  __shared__ float red[256];
  __shared__ float thr;
  int i = blockIdx.x;
  int t = threadIdx.x;
  const float* row = partial + (size_t)i * PCOLS;
  float best = INFINITY;
  for (int e = t; e < PCOLS; e += 256) best = fminf(best, row[e]);
  red[t] = best;
  __syncthreads();
  for (int s = 128; s > 0; s >>= 1) {
    if (t < s) red[t] = fminf(red[t], red[t + s]);
    __syncthreads();
  }
  if (t == 0) thr = red[0] + DELTA2;
  __syncthreads();
  float th = thr;
  for (int e = t; e < PCOLS; e += 256) {
    if (row[e] <= th) {
      unsigned int pos = atomicAdd(cnt, 1u);
      list[pos] = ((unsigned int)i << 12) | (unsigned int)e;
    }
  }
}

// ===== exact fp32 rescore of candidate granules -> pmin (packed atomicMin) =====
__global__ __launch_bounds__(256) void k_rescore(const unsigned int* __restrict__ list,
                                                 const unsigned int* __restrict__ cnt,
                                                 const float* __restrict__ patch,
                                                 const float* __restrict__ lib,
                                                 const float* __restrict__ a2,
                                                 const float* __restrict__ b2,
                                                 unsigned long long* __restrict__ pmin) {
  int wid = (blockIdx.x << 2) | (threadIdx.x >> 6);
  int lane = threadIdx.x & 63;
  int n = (int)*cnt;
  for (int c = wid; c < n; c += RESCORE_WAVES) {
    unsigned int e = list[c];
    int i = (int)(e >> 12);
    int g = (int)(e & 4095u);
    int j = (g << 6) + lane;
    unsigned long long best = ~0ull;
    if (j < NL) {
      const float* pr = patch + (size_t)i * DIM;
      const float* lr = lib + (size_t)j * DIM;
      float d0 = 0.f, d1 = 0.f, d2s = 0.f, d3 = 0.f;
#pragma unroll 8
      for (int k = 0; k < DIM; k += 4) {
        float4 lv = *(const float4*)(lr + k);
        float4 pv = *(const float4*)(pr + k);
        d0 = fmaf(lv.x, pv.x, d0);
        d1 = fmaf(lv.y, pv.y, d1);
        d2s = fmaf(lv.z, pv.z, d2s);
        d3 = fmaf(lv.w, pv.w, d3);
      }
      float dot = (d0 + d1) + (d2s + d3);
      float d2 = fmaxf(a2[i] + b2[j] - 2.f * dot, 0.f);
      best = packdj(d2, j);
    }
#pragma unroll
    for (int mm = 1; mm < 64; mm <<= 1) {
      unsigned long long o = __shfl_xor(best, mm);
      best = (o < best) ? o : best;
    }
    if (lane == 0) atomicMin(pmin + i, best);
  }
}

// ---------- finalize1: min_val = sqrt(d2min); s_star/s_idx (jnp tie-break) ----------
__global__ __launch_bounds__(256) void k_final1(const unsigned long long* __restrict__ pmin,
                                                float* __restrict__ minval,
                                                float* __restrict__ scalf,
                                                int* __restrict__ scali) {
  __shared__ float sv[256];
  __shared__ int si[256];
  int t = threadIdx.x;
  float bv = -1.f; int bi = 1 << 30;
  for (int i = t; i < NP; i += 256) {
    unsigned long long p = pmin[i];
    float d2 = __uint_as_float((unsigned int)(p >> 32));
    float v = sqrtf(d2);
    minval[i] = v;
    if (v > bv) { bv = v; bi = i; }
  }
  sv[t] = bv; si[t] = bi;
  __syncthreads();
  for (int s = 128; s > 0; s >>= 1) {
    if (t < s) {
      if (sv[t + s] > sv[t] || (sv[t + s] == sv[t] && si[t + s] < si[t])) {
        sv[t] = sv[t + s]; si[t] = si[t + s];
      }
    }
    __syncthreads();
  }
  if (t == 0) {
    scalf[0] = sv[0];
    scali[0] = si[0];
    scali[1] = (int)(unsigned int)(pmin[si[0]] & 0xFFFFFFFFull);
  }
}

// ---------- bilinear 28x28 -> 224x224 ----------
__global__ __launch_bounds__(256) void k_resize(const float* __restrict__ mv,
                                                float* __restrict__ out) {
  int o = blockIdx.x * 256 + threadIdx.x;
  if (o >= 224 * 224) return;
  int y = o / 224, x = o - y * 224;
  float sy = (y + 0.5f) * 0.125f - 0.5f;
  float sx = (x + 0.5f) * 0.125f - 0.5f;
  int y0 = (int)floorf(sy); float fy = sy - (float)y0;
  int x0 = (int)floorf(sx); float fx = sx - (float)x0;
  int y0c = max(y0, 0), y1c = min(y0 + 1, 27);
  int x0c = max(x0, 0), x1c = min(x0 + 1, 27);
  float v00 = mv[y0c * 28 + x0c], v01 = mv[y0c * 28 + x1c];
  float v10 = mv[y1c * 28 + x0c], v11 = mv[y1c * 28 + x1c];
  float v0 = v00 + fx * (v01 - v00);
  float v1 = v10 + fx * (v11 - v10);
  out[1 + o] = v0 + fy * (v1 - v0);
}

// ===== approx w_dist^2 via Bh (bf16) GEMV; store wd2[j]; per-block top-3  [verified R5] =====
__global__ __launch_bounds__(256) void k_wdist(const unsigned short* __restrict__ Bh,
                                               const float* __restrict__ b2,
                                               const int* __restrict__ scali,
                                               float* __restrict__ wd2,
                                               unsigned long long* __restrict__ top3w) {
  __shared__ unsigned long long sm[12];
  int wave = threadIdx.x >> 6, lane = threadIdx.x & 63;
  int jstar = scali[1];
  const unsigned* msrow = (const unsigned*)(Bh + (size_t)jstar * DIM);
  float ms[6];
#pragma unroll
  for (int it = 0; it < 3; ++it) {
    unsigned u = msrow[(it << 6) + lane];
    ms[it * 2] = bf16lo(u);
    ms[it * 2 + 1] = bf16hi(u);
  }
  float bstar = b2[jstar];
  unsigned long long t0 = ~0ull, t1 = ~0ull, t2 = ~0ull;
  int gw = (blockIdx.x << 2) | wave;
  for (int j = gw; j < NL; j += WTOP_BLOCKS * 4) {
    const unsigned* row = (const unsigned*)(Bh + (size_t)j * DIM);
    float dot = 0.f;
#pragma unroll
    for (int it = 0; it < 3; ++it) {
      unsigned u = row[(it << 6) + lane];
      dot = fmaf(ms[it * 2], bf16lo(u), dot);
      dot = fmaf(ms[it * 2 + 1], bf16hi(u), dot);
    }
#pragma unroll
    for (int mm = 1; mm < 64; mm <<= 1) dot += __shfl_xor(dot, mm);
    float d2 = fmaxf(bstar + b2[j] - 2.f * dot, 0.f);
    if (lane == 0) wd2[j] = d2;
    ins3(t0, t1, t2, packdj(d2, j));
  }
  if (lane == 0) { sm[wave * 3] = t0; sm[wave * 3 + 1] = t1; sm[wave * 3 + 2] = t2; }
  __syncthreads();
  if (threadIdx.x == 0) {
    unsigned long long a0 = ~0ull, a1 = ~0ull, a2v = ~0ull;
    for (int e = 0; e < 12; ++e) ins3(a0, a1, a2v, sm[e]);
    top3w[blockIdx.x * 3 + 0] = a0;
    top3w[blockIdx.x * 3 + 1] = a1;
    top3w[blockIdx.x * 3 + 2] = a2v;
  }
}

// ===== merge approx top-3 -> threshold for w candidates  [verified R5] =====
__global__ __launch_bounds__(256) void k_wsel1(const unsigned long long* __restrict__ top3w,
                                               float* __restrict__ scalf) {
  __shared__ unsigned long long sm[768];
  int t = threadIdx.x;
  unsigned long long t0 = ~0ull, t1 = ~0ull, t2 = ~0ull;
  for (int e = t; e < WTOP_BLOCKS * 3; e += 256) ins3(t0, t1, t2, top3w[e]);
  sm[t] = t0; sm[256 + t] = t1; sm[512 + t] = t2;
  __syncthreads();
  if (t == 0) {
    unsigned long long a0 = ~0ull, a1 = ~0ull, a2v = ~0ull;
    for (int e = 0; e < 768; ++e) ins3(a0, a1, a2v, sm[e]);
    scalf[1] = __uint_as_float((unsigned int)(a2v >> 32)) + DELTAW;
  }
}

// ===== collect all j with wd2 <= thr  [verified R5] =====
__global__ __launch_bounds__(256) void k_wsel2(const float* __restrict__ wd2,
                                               const float* __restrict__ scalf,
                                               unsigned int* __restrict__ wlist,
                                               unsigned int* __restrict__ wcnt) {
  float thr = scalf[1];
  for (int j = blockIdx.x * 256 + threadIdx.x; j < NL; j += 256 * 256) {
    if (wd2[j] <= thr) {
      unsigned int pos = atomicAdd(wcnt, 1u);
      if (pos < WCAP) wlist[pos] = (unsigned int)j;
    }
  }
}

// ===== exact rescore of w candidates -> exact top-3 -> final s  [verified R5] =====
__global__ __launch_bounds__(256) void k_finals2(const float* __restrict__ patch,
                                                 const float* __restrict__ lib,
                                                 const float* __restrict__ b2,
                                                 const unsigned int* __restrict__ wlist,
                                                 const unsigned int* __restrict__ wcnt,
                                                 const float* __restrict__ scalf,
                                                 const int* __restrict__ scali,
                                                 float* __restrict__ out) {
  __shared__ unsigned long long pk[WCAP];
  __shared__ int snn[2];
  __shared__ float sd[2];
  int t = threadIdx.x, wv = t >> 6, lane = t & 63;
  int n = min((int)*wcnt, WCAP);
  int jstar = scali[1];
  const float* mstar = lib + (size_t)jstar * DIM;
  float bstar = b2[jstar];
  for (int c = wv; c < n; c += 4) {
    int j = (int)wlist[c];
    const float* lr = lib + (size_t)j * DIM;
    float s = 0.f;
#pragma unroll
    for (int q = 0; q < 6; ++q)
      s = fmaf(mstar[lane + (q << 6)], lr[lane + (q << 6)], s);
#pragma unroll
    for (int mm = 1; mm < 64; mm <<= 1) s += __shfl_xor(s, mm);
    if (lane == 0) pk[c] = packdj(fmaxf(bstar + b2[j] - 2.f * s, 0.f), j);
  }
  __syncthreads();
  if (t == 0) {
    unsigned long long a0 = ~0ull, a1 = ~0ull, a2v = ~0ull;
    for (int e = 0; e < n; ++e) ins3(a0, a1, a2v, pk[e]);
    snn[0] = (int)(unsigned int)(a1 & 0xFFFFFFFFull);   // nn_idx[1]
    snn[1] = (int)(unsigned int)(a2v & 0xFFFFFFFFull);  // nn_idx[2]
  }
  __syncthreads();
  if (t < 128) {
    const float* mt = patch + (size_t)scali[0] * DIM;
    const float* bp = lib + (size_t)snn[wv] * DIM;
    float s = 0.f;
#pragma unroll
    for (int q = 0; q < 6; ++q) {
      float d = mt[lane + (q << 6)] - bp[lane + (q << 6)];
      s = fmaf(d, d, s);
    }
#pragma unroll
    for (int mm = 1; mm < 64; mm <<= 1) s += __shfl_xor(s, mm);
    if (lane == 0) sd[wv] = sqrtf(fmaxf(s, 0.f));
  }
  __syncthreads();
  if (t == 0) {
    const float Ds = 19.595917942265423f;  // sqrt(384)
    float sstar = scalf[0];
    float w = 1.f - expf(sstar / Ds) / (expf(sd[0] / Ds) + expf(sd[1] / Ds));
    out[0] = w * sstar;
  }
}

// ======= fallback fp32 path kernels (used only if ws_size is too small) =======
__global__ __launch_bounds__(256) void k_norms(const float* __restrict__ patch,
                                               const float* __restrict__ lib,
                                               float* __restrict__ a2,
                                               float* __restrict__ b2) {
  int wave = (blockIdx.x << 2) | (threadIdx.x >> 6);
  int lane = threadIdx.x & 63;
  const int NR = NL + NP;
  if (wave >= NR) return;
  const float* src = (wave < NL) ? (lib + (size_t)wave * DIM)
                                 : (patch + (size_t)(wave - NL) * DIM);
  float s = 0.f;
#pragma unroll
  for (int m = 0; m < 6; ++m) { float v = src[lane + (m << 6)]; s += v * v; }
#pragma unroll
  for (int m = 1; m < 64; m <<= 1) s += __shfl_xor(s, m);
  if (lane == 0) { if (wave < NL) b2[wave] = s; else a2[wave - NL] = s; }
}

__global__ __launch_bounds__(256) void k_distmin(const float* __restrict__ patch,
                                                 const float* __restrict__ lib,
                                                 const float* __restrict__ a2,
                                                 const float* __restrict__ b2,
                                                 unsigned long long* __restrict__ pmin) {
  __shared__ float As[16][68];
  __shared__ float Bs[16][68];
  const int t = threadIdx.x;
  const int lr = t >> 2;
  const int lc = (t & 3) << 2;
  const int ti = t >> 4;
  const int tj = t & 15;
  const int i0 = blockIdx.y << 6;
  const int j0 = blockIdx.x << 6;
  const bool a_ok = (i0 + lr) < NP;
  const float* ap = patch + (size_t)(i0 + lr) * DIM + lc;
  const float* bp = lib + (size_t)(j0 + lr) * DIM + lc;

  float acc[4][4] = {};
  for (int k0 = 0; k0 < DIM; k0 += 16) {
    float4 avv = make_float4(0.f, 0.f, 0.f, 0.f);
    if (a_ok) avv = *(const float4*)(ap + k0);
    float4 bvv = *(const float4*)(bp + k0);
    __syncthreads();
    As[lc + 0][lr] = avv.x; As[lc + 1][lr] = avv.y;
    As[lc + 2][lr] = avv.z; As[lc + 3][lr] = avv.w;
    Bs[lc + 0][lr] = bvv.x; Bs[lc + 1][lr] = bvv.y;
    Bs[lc + 2][lr] = bvv.z; Bs[lc + 3][lr] = bvv.w;
    __syncthreads();
#pragma unroll
    for (int kk = 0; kk < 16; ++kk) {
      float4 a = *(const float4*)&As[kk][ti << 2];
      float4 b = *(const float4*)&Bs[kk][tj << 2];
      acc[0][0] += a.x * b.x; acc[0][1] += a.x * b.y; acc[0][2] += a.x * b.z; acc[0][3] += a.x * b.w;
      acc[1][0] += a.y * b.x; acc[1][1] += a.y * b.y; acc[1][2] += a.y * b.z; acc[1][3] += a.y * b.w;
      acc[2][0] += a.z * b.x; acc[2][1] += a.z * b.y; acc[2][2] += a.z * b.z; acc[2][3] += a.z * b.w;
      acc[3][0] += a.w * b.x; acc[3][1] += a.w * b.y; acc[3][2] += a.w * b.z; acc[3][3] += a.w * b.w;
    }
  }
#pragma unroll
  for (int r = 0; r < 4; ++r) {
    int i = i0 + (ti << 2) + r;
    unsigned long long best = ~0ull;
    if (i < NP) {
      float ai = a2[i];
#pragma unroll
      for (int c = 0; c < 4; ++c) {
        int j = j0 + (tj << 2) + c;
        float d2 = fmaxf(ai + b2[j] - 2.f * acc[r][c], 0.f);
        unsigned long long p = packdj(d2, j);
        best = (p < best) ? p : best;
      }
    }
#pragma unroll
    for (int m = 1; m < 16; m <<= 1) {
      unsigned long long o = __shfl_xor(best, m);
      best = (o < best) ? o : best;
    }
    if (tj == 0 && i < NP) atomicMin(pmin + i, best);
  }
}

__global__ __launch_bounds__(256) void k_wtop(const float* __restrict__ lib,
                                              const int* __restrict__ scali,
                                              unsigned long long* __restrict__ top3) {
  __shared__ unsigned long long sm[12];
  int wave = threadIdx.x >> 6, lane = threadIdx.x & 63;
  int jstar = scali[1];
  const float* ms = lib + (size_t)jstar * DIM;
  float m[6];
#pragma unroll
  for (int q = 0; q < 6; ++q) m[q] = ms[lane + (q << 6)];
  unsigned long long t0 = ~0ull, t1 = ~0ull, t2 = ~0ull;
  int gw = (blockIdx.x << 2) | wave;
  for (int j = gw; j < NL; j += WTOP_BLOCKS * 4) {
    const float* bp = lib + (size_t)j * DIM;
    float s = 0.f;
#pragma unroll
    for (int q = 0; q < 6; ++q) { float d = bp[lane + (q << 6)] - m[q]; s += d * d; }
#pragma unroll
    for (int mm = 1; mm < 64; mm <<= 1) s += __shfl_xor(s, mm);
    ins3(t0, t1, t2, packdj(fmaxf(s, 0.f), j));
  }
  if (lane == 0) { sm[wave * 3] = t0; sm[wave * 3 + 1] = t1; sm[wave * 3 + 2] = t2; }
  __syncthreads();
  if (threadIdx.x == 0) {
    unsigned long long a0 = ~0ull, a1 = ~0ull, a2v = ~0ull;
    for (int e = 0; e < 12; ++e) ins3(a0, a1, a2v, sm[e]);
    top3[blockIdx.x * 3 + 0] = a0;
    top3[blockIdx.x * 3 + 1] = a1;
    top3[blockIdx.x * 3 + 2] = a2v;
  }
}

__global__ __launch_bounds__(256) void k_finals(const float* __restrict__ patch,
                                                const float* __restrict__ lib,
                                                const unsigned long long* __restrict__ top3,
                                                const float* __restrict__ scalf,
                                                const int* __restrict__ scali,
                                                float* __restrict__ out) {
  __shared__ unsigned long long sm[768];
  __shared__ int snn[2];
  __shared__ float sd[2];
  int t = threadIdx.x;
  unsigned long long t0 = ~0ull, t1 = ~0ull, t2 = ~0ull;
  for (int e = t; e < WTOP_BLOCKS * 3; e += 256) ins3(t0, t1, t2, top3[e]);
  sm[t] = t0; sm[256 + t] = t1; sm[512 + t] = t2;
  __syncthreads();
  if (t == 0) {
    unsigned long long a0 = ~0ull, a1 = ~0ull, a2v = ~0ull;
    for (int e = 0; e < 768; ++e) ins3(a0, a1, a2v, sm[e]);
    snn[0] = (int)(unsigned int)(a1 & 0xFFFFFFFFull);
    snn[1] = (int)(unsigned int)(a2v & 0xFFFFFFFFull);
  }
  __syncthreads();
  if (t < 128) {
    int wv = t >> 6, lane = t & 63;
    const float* mt = patch + (size_t)scali[0] * DIM;
    const float* bp = lib + (size_t)snn[wv] * DIM;
    float s = 0.f;
#pragma unroll
    for (int q = 0; q < 6; ++q) {
      float d = mt[lane + (q << 6)] - bp[lane + (q << 6)];
      s += d * d;
    }
#pragma unroll
    for (int mm = 1; mm < 64; mm <<= 1) s += __shfl_xor(s, mm);
    if (lane == 0) sd[wv] = sqrtf(fmaxf(s, 0.f));
  }
  __syncthreads();
  if (t == 0) {
    const float Ds = 19.595917942265423f;
    float sstar = scalf[0];
    float w = 1.f - expf(sstar / Ds) / (expf(sd[0] / Ds) + expf(sd[1] / Ds));
    out[0] = w * sstar;
  }
}

extern "C" void kernel_launch(void* const* d_in, const int* in_sizes, int n_in,
                              void* d_out, int out_size, void* d_ws, size_t ws_size,
                              hipStream_t stream) {
  const float* patch = (const float*)d_in[0];
  const float* lib = (const float*)d_in[1];
  float* out = (float*)d_out;
  char* ws = (char*)d_ws;

  const size_t SZ_BPLANE = (size_t)NLPAD * DIM * 2;          // 153,649,152
  const size_t SZ_APLANE = (size_t)MPAD * DIM * 2;           // 688,128
  const size_t SZ_PART = (size_t)NP * PCOLS * 4;             // 9,803,136
  const size_t SZ_LIST = (size_t)NP * PCOLS * 4;             // 9,803,136
  const size_t SZ_WD2 = (size_t)NLPAD * 4;                   // 800,256
  const size_t NEED = SZ_BPLANE + SZ_APLANE + SZ_PART + SZ_LIST + SZ_WD2 + 4 * 1024 * 1024;

  if (ws_size >= NEED) {
    size_t off = 0;
    unsigned short* Bh = (unsigned short*)(ws + off); off += SZ_BPLANE;
    unsigned short* Ah = (unsigned short*)(ws + off); off += SZ_APLANE;
    float* partial = (float*)(ws + off); off += SZ_PART;
    unsigned int* list = (unsigned int*)(ws + off); off += SZ_LIST;
    float* wd2 = (float*)(ws + off); off += SZ_WD2;
    float* b2 = (float*)(ws + off); off += (size_t)NLPAD * 4;
    float* a2 = (float*)(ws + off); off += (size_t)MPAD * 4;
    unsigned long long* pmin = (unsigned long long*)(ws + off); off += NP * 8;
    unsigned long long* top3w = (unsigned long long*)(ws + off); off += WTOP_BLOCKS * 3 * 8;
    unsigned int* wlist = (unsigned int*)(ws + off); off += WCAP * 4;
    float* minval = (float*)(ws + off); off += NP * 4;
    float* scalf = (float*)(ws + off); off += 16;
    int* scali = (int*)(ws + off); off += 16;
    unsigned int* cnt = (unsigned int*)(ws + off); off += 32;  // cnt at +0, wcnt at +4

    hipMemsetAsync(pmin, 0xFF, NP * sizeof(unsigned long long), stream);
    hipMemsetAsync(cnt, 0, 32, stream);

    k_prep_a<<<MPAD / 4, 256, 0, stream>>>(patch, Ah, a2);
    k_prep_b<<<NLPAD / 4, 256, 0, stream>>>(lib, Bh, b2);
    k_gemm<<<MTILES * NTILES, 256, 0, stream>>>(Ah, Bh, b2, partial);
    k_scan_select<<<NP, 256, 0, stream>>>(partial, list, cnt);
    k_rescore<<<RESCORE_WAVES / 4, 256, 0, stream>>>(list, cnt, patch, lib, a2, b2, pmin);
    k_final1<<<1, 256, 0, stream>>>(pmin, minval, scalf, scali);
    k_resize<<<(224 * 224 + 255) / 256, 256, 0, stream>>>(minval, out);
    k_wdist<<<WTOP_BLOCKS, 256, 0, stream>>>(Bh, b2, scali, wd2, top3w);
    k_wsel1<<<1, 256, 0, stream>>>(top3w, scalf);
    k_wsel2<<<256, 256, 0, stream>>>(wd2, scalf, wlist, cnt + 1);
    k_finals2<<<1, 256, 0, stream>>>(patch, lib, b2, wlist, cnt + 1, scalf, scali, out);
  } else {
    // fallback: fp32 VALU path (verified R1)
    float* b2 = (float*)ws;
    float* a2 = (float*)(ws + 800000);
    unsigned long long* pmin = (unsigned long long*)(ws + 803200);
    unsigned long long* top3 = (unsigned long long*)(ws + 809472);
    float* minval = (float*)(ws + 821760);
    float* scalf = (float*)(ws + 824896);
    int* scali = (int*)(ws + 824912);

    hipMemsetAsync(pmin, 0xFF, NP * sizeof(unsigned long long), stream);
    k_norms<<<(NL + NP + 3) / 4, 256, 0, stream>>>(patch, lib, a2, b2);
    dim3 grid(NL / 64, (NP + 63) / 64);
    k_distmin<<<grid, 256, 0, stream>>>(patch, lib, a2, b2, pmin);
    k_final1<<<1, 256, 0, stream>>>(pmin, minval, scalf, scali);
    k_resize<<<(224 * 224 + 255) / 256, 256, 0, stream>>>(minval, out);
    k_wtop<<<WTOP_BLOCKS, 256, 0, stream>>>(lib, scali, top3);
    k_finals<<<1, 256, 0, stream>>>(patch, lib, top3, scalf, scali, out);
  }
}